// Round 6
// baseline (20419.550 us; speedup 1.0000x reference)
//
#include <hip/hip_runtime.h>

// ---------------------------------------------------------------------------
// 2-layer LSTM (B=4096, H=512, T=100) + per-step FC(63), fp16 MFMA.
// 32 teams (128 batch rows) x 8 blocks (64 hidden units). c-state in regs,
// x0 fp16 L2-resident, weights direct-from-L2 (never invalidated, 1-chunk
// register prefetch), h exchanged via asm sc0/sc1 scalar loads/stores through
// L3; fence-free flag barrier (R1-proven atomics); A staged via 4-buffer LDS,
// one explicit vmcnt(0) per 2 chunks, loads issued a full iteration ahead.
// ---------------------------------------------------------------------------

#define HIDN  512
#define SEQL  100
#define BATCH 4096
#define NB    8
#define BR    128

typedef _Float16 f16;
typedef _Float16 half8 __attribute__((ext_vector_type(8)));
typedef float    f32x4 __attribute__((ext_vector_type(4)));

// ws layout (bytes)
#define OFF_XCAT   0ul
#define OFF_X0PT   (OFF_XCAT + 256ul*4096*4)
#define OFF_WP0    (OFF_X0PT + 2048ul*4096*4)
#define OFF_WP1I   (OFF_WP0  + 2048ul*512*2)
#define OFF_WP1H   (OFF_WP1I + 2048ul*512*2)
#define OFF_FCW    (OFF_WP1H + 2048ul*512*2)
#define OFF_B1P    (OFF_FCW  + 64ul*512*2)
#define OFF_H0     (OFF_B1P  + 2048ul*4)
#define OFF_H1     (OFF_H0   + 2ul*4096*512*2)
#define OFF_FLAGS  (OFF_H1   + 2ul*4096*512*2)
#define FLAG_BYTES (32ul*128*4)

__device__ __forceinline__ int orow(int pr){
  return (((pr>>6)&3)<<9) | ((pr>>8)<<6) | (pr&63);
}
__device__ __forceinline__ float sigm(float x){ return 1.f/(1.f + __expf(-x)); }
__device__ __forceinline__ float tanhx(float x){ return 1.f - 2.f/(1.f + __expf(2.f*x)); }
__device__ __forceinline__ f32x4 splat4(float v){ f32x4 r; r[0]=v; r[1]=v; r[2]=v; r[3]=v; return r; }

// ---- coherent memory ops: SCALAR asm operands only ----
__device__ __forceinline__ unsigned int ld_coh_u32(const void* p){
  unsigned int r;
  asm volatile("global_load_dword %0, %1, off sc0 sc1"
               : "=v"(r) : "v"(p) : "memory");
  return r;
}
__device__ __forceinline__ void st_coh_u16(void* p, unsigned int d){
  asm volatile("global_store_short %0, %1, off sc0 sc1"
               :: "v"(p), "v"(d) : "memory");
}
__device__ __forceinline__ void wait_vm0(){
  asm volatile("s_waitcnt vmcnt(0)" ::: "memory");
}
__device__ __forceinline__ unsigned int f16bits(float x){
  union { f16 h; unsigned short s; } u;
  u.h = (f16)x;
  return (unsigned int)u.s;
}

// ---------------- prep 1: xcatT[c][b] ----------------------------------------
__global__ __launch_bounds__(256) void k_xcat(
    const int* __restrict__ sl, const int* __restrict__ el,
    const float* __restrict__ sc, const float* __restrict__ ec,
    const float* __restrict__ emb, float* __restrict__ xcatT)
{
  int b = blockIdx.x*256 + threadIdx.x;
  int c = blockIdx.y;
  float v = 0.f;
  if      (c < 64 ) v = emb[sl[b]*64 + c];
  else if (c < 128) v = emb[el[b]*64 + (c-64)];
  else if (c < 191) v = sc[b*63 + (c-128)];
  else if (c < 254) v = ec[b*63 + (c-191)];
  xcatT[c*4096 + b] = v;
}

// ---------------- prep 2: pack weights fp16, fc, biases ----------------------
__global__ __launch_bounds__(256) void k_pack(
    const float* __restrict__ Whh0, const float* __restrict__ Wih1,
    const float* __restrict__ Whh1, const float* __restrict__ fcW,
    const float* __restrict__ bih1, const float* __restrict__ bhh1,
    f16* __restrict__ Wp0, f16* __restrict__ Wp1i, f16* __restrict__ Wp1h,
    f16* __restrict__ fcWp, float* __restrict__ b1p)
{
  int row = blockIdx.x, tid = threadIdx.x;
  if (row < 6144){
    int m  = row >> 11;
    int pr = row & 2047;
    const float* src = (m==0) ? Whh0 : (m==1) ? Wih1 : Whh1;
    f16* dst = (m==0) ? Wp0 : (m==1) ? Wp1i : Wp1h;
    int orig = orow(pr);
    dst[pr*512 + tid      ] = (f16)src[orig*512 + tid      ];
    dst[pr*512 + tid + 256] = (f16)src[orig*512 + tid + 256];
  } else if (row < 6208){
    int n = row - 6144;
    float v0 = (n < 63) ? fcW[n*512 + tid      ] : 0.f;
    float v1 = (n < 63) ? fcW[n*512 + tid + 256] : 0.f;
    fcWp[n*512 + tid] = (f16)v0; fcWp[n*512 + tid + 256] = (f16)v1;
  } else {
    int j = row - 6208;
    int orig = (((tid>>6)&3)<<9) | (j<<6) | (tid&63);
    b1p[j*256 + tid] = bih1[orig] + bhh1[orig];
  }
}

// ---------------- prep 3: x0ph[pr][b] (fp16), LDS-staged W, scalar reads -----
__global__ __launch_bounds__(256) void k_x0(
    const float* __restrict__ xcatT, const float* __restrict__ Wih0,
    const float* __restrict__ bih0, const float* __restrict__ bhh0,
    f16* __restrict__ x0ph)
{
  __shared__ float Wl[32*256];
  __shared__ float bl[32];
  const int tid = threadIdx.x;
  const int pr0 = blockIdx.x * 32;
  const int b   = blockIdx.y * 256 + tid;
  for (int idx = tid; idx < 32*256; idx += 256){
    int r = idx >> 8, k = idx & 255;
    Wl[idx] = (k < 254) ? Wih0[orow(pr0+r)*254 + k] : 0.f;
  }
  if (tid < 32){
    int orig = orow(pr0+tid);
    bl[tid] = bih0[orig] + bhh0[orig];
  }
  __syncthreads();
  float a[32];
#pragma unroll
  for (int r=0;r<32;r++) a[r] = 0.f;
  for (int k=0; k<254; k++){
    float xv = xcatT[k*4096 + b];
#pragma unroll
    for (int r=0;r<32;r++)
      a[r] = fmaf(xv, Wl[r*256 + k], a[r]);
  }
#pragma unroll
  for (int r=0;r<32;r++)
    x0ph[(size_t)(pr0+r)*4096 + b] = (f16)(a[r] + bl[r]);
}

// ---------------- main persistent LSTM kernel --------------------------------
__global__ __launch_bounds__(512, 2) void k_lstm(
    const f16* __restrict__ x0ph, const f16* __restrict__ Wp0,
    const f16* __restrict__ Wp1i, const f16* __restrict__ Wp1h,
    const f16* __restrict__ fcWp, const float* __restrict__ b1p,
    const float* __restrict__ fcb, f16* __restrict__ h0buf,
    f16* __restrict__ h1buf, unsigned int* __restrict__ flags,
    float* __restrict__ out)
{
  __shared__ __align__(16) f16 Ach[4][128*40];   // A staging, 4 buffers (40 KB)

  const int tid  = threadIdx.x;
  const int blk  = blockIdx.x;
  const int j    = blk & 7;        // hidden slice == XCD (%8 round robin)
  const int team = blk >> 3;
  const int b0   = team * BR;
  const int w = tid >> 6, wr = w >> 2, wc = w & 3;
  const int lane = tid & 63, quad = lane >> 4, lc = lane & 15;
  const int ucol = wc*16 + lc;
  const bool des = (j == (team & 7));

  const f16* Wb0  = Wp0  + (size_t)(j*256)*512;
  const f16* Wb1i = Wp1i + (size_t)(j*256)*512;
  const f16* Wb1h = Wp1h + (size_t)(j*256)*512;
  const f16* xb   = x0ph + (size_t)(j*256)*4096 + b0;

  const int srA   = tid >> 2;
  const int ssg   = (tid & 3) * 8;
  const int Aoff  = srA*HIDN + ssg;
  const int boffB = ucol*512 + quad*8;
  unsigned int* tflags = flags + team*128;

  float b1v[4];
#pragma unroll
  for (int g=0; g<4; g++) b1v[g] = b1p[j*256 + g*64 + ucol];
  const float fcbv = (ucol < 63) ? fcb[ucol] : 0.f;

  f32x4 c0[4], c1[4];
#pragma unroll
  for (int mt=0; mt<4; mt++){ c0[mt] = splat4(0.f); c1[mt] = splat4(0.f); }

  // fence-free team barrier (R1-proven atomic forms). wait_vm0 drains our
  // asm sc0/sc1 stores (compiler doesn't track them) before the flag add.
  auto barrier = [&](int idx){
    wait_vm0();
    __syncthreads();
    if (tid == 0){
      __hip_atomic_fetch_add(&tflags[idx], 1u, __ATOMIC_RELAXED, __HIP_MEMORY_SCOPE_AGENT);
      while (__hip_atomic_load(&tflags[idx], __ATOMIC_RELAXED, __HIP_MEMORY_SCOPE_AGENT) < (unsigned)NB)
        __builtin_amdgcn_s_sleep(4);
    }
    __syncthreads();
  };

  // GEMM over nch K-chunks of 32. A via coherent scalar asm loads -> 4-buffer
  // LDS; one explicit vmcnt(0) per 2 chunks, loads issued a full iteration
  // ahead. B via plain L2-cached loads, register-prefetched per chunk.
  auto GEMM = [&](int nch, int wsw, const f16* A1, const f16* A2,
                  const f16* W1, const f16* W2, f32x4 (&acc)[4][4],
                  bool dofc, f32x4* fca, int fck0){
    unsigned int rA[4], rB[4];
    auto ldp = [&](int kc, unsigned int* r){
      const f16* p = (kc < wsw ? A1 + kc*32 : A2 + (kc-wsw)*32) + Aoff;
      const unsigned int* q = (const unsigned int*)p;
      r[0] = ld_coh_u32(q+0); r[1] = ld_coh_u32(q+1);
      r[2] = ld_coh_u32(q+2); r[3] = ld_coh_u32(q+3);
    };
    auto stp = [&](int kc, const unsigned int* r){
      unsigned int* d = (unsigned int*)&Ach[kc&3][srA*40 + ssg];
      d[0]=r[0]; d[1]=r[1]; d[2]=r[2]; d[3]=r[3];
    };
    auto Bld = [&](int kc, half8* bf){
      const f16* WB = (kc < wsw ? W1 + kc*32 : W2 + (kc-wsw)*32) + boffB;
#pragma unroll
      for (int g=0; g<4; g++) bf[g] = *(const half8*)(WB + g*32768);
    };
    auto comp = [&](int kc, const half8* bf){
      const int bu = kc&3;
      half8 af[4];
#pragma unroll
      for (int mt=0; mt<4; mt++)
        af[mt] = *(const half8*)&Ach[bu][(wr*64 + mt*16 + lc)*40 + quad*8];
#pragma unroll
      for (int g=0; g<4; g++)
#pragma unroll
        for (int mt=0; mt<4; mt++)
          acc[g][mt] = __builtin_amdgcn_mfma_f32_16x16x32_f16(af[mt], bf[g], acc[g][mt], 0, 0, 0);
      if (dofc && kc >= fck0){
        half8 fb = *(const half8*)(fcWp + boffB + (kc-fck0)*32);
#pragma unroll
        for (int mt=0; mt<4; mt++)
          fca[mt] = __builtin_amdgcn_mfma_f32_16x16x32_f16(af[mt], fb, fca[mt], 0, 0, 0);
      }
    };

    half8 bfE[4], bfO[4];
    ldp(0, rA); ldp(1, rB);
    wait_vm0();
    stp(0, rA); stp(1, rB);
    ldp(2, rA); ldp(3, rB);
    Bld(0, bfE);
    for (int kc=0; kc<nch; kc+=2){
      __syncthreads();           // LDS: prev writes visible / reads done
      wait_vm0();                // asm loads for chunks kc+2, kc+3 complete
      if (kc+2 < nch) stp(kc+2, rA);
      if (kc+3 < nch) stp(kc+3, rB);
      if (kc+4 < nch) ldp(kc+4, rA);
      if (kc+5 < nch) ldp(kc+5, rB);
      Bld(kc+1, bfO);
      comp(kc, bfE);
      if (kc+2 < nch) Bld(kc+2, bfE);
      comp(kc+1, bfO);
    }
  };

  f32x4 fcd[4];   // dummy fc accumulator for non-fc GEMM calls

  for (int t=0; t<SEQL; t++){
    const int p  = t & 1;
    const int pp = (t-1) & 1;
    const f16* h0rd = h0buf + (size_t)pp*BATCH*HIDN + (size_t)b0*HIDN;
    const f16* h1rd = h1buf + (size_t)pp*BATCH*HIDN + (size_t)b0*HIDN;
    f16* h0wr = h0buf + (size_t)p*BATCH*HIDN;
    f16* h1wr = h1buf + (size_t)p*BATCH*HIDN;

    // ----- layer 0: acc = x0 (fp16, scalar loads) + h0(t-1) @ Whh0^T -----
    f32x4 acc[4][4];
#pragma unroll
    for (int g=0; g<4; g++)
#pragma unroll
      for (int mt=0; mt<4; mt++){
        const f16* xp = xb + (size_t)(g*64 + ucol)*4096 + wr*64 + mt*16 + quad*4;
        f32x4 a;
        a[0]=(float)xp[0]; a[1]=(float)xp[1]; a[2]=(float)xp[2]; a[3]=(float)xp[3];
        acc[g][mt] = a;
      }
    if (t > 0)
      GEMM(16, 16, h0rd, h0rd, Wb0, Wb0, acc, false, fcd, 0);
#pragma unroll
    for (int mt=0; mt<4; mt++){
#pragma unroll
      for (int r=0; r<4; r++){
        float iv = sigm(acc[0][mt][r]);
        float fv = sigm(acc[1][mt][r]);
        float gv = tanhx(acc[2][mt][r]);
        float ov = sigm(acc[3][mt][r]);
        float cn = fv*c0[mt][r] + iv*gv;
        c0[mt][r] = cn;
        float hn = ov * tanhx(cn);
        int row = wr*64 + mt*16 + quad*4 + r;
        st_coh_u16(h0wr + (size_t)(b0+row)*HIDN + j*64 + ucol, f16bits(hn));
      }
    }
    barrier(t);   // drains h0 stores, then team flag sync

    // ----- layer 1 (+ fused fc for y(t-1) on designated block) -----
    const f16* h0cur = h0buf + (size_t)p*BATCH*HIDN + (size_t)b0*HIDN;
#pragma unroll
    for (int g=0; g<4; g++)
#pragma unroll
      for (int mt=0; mt<4; mt++)
        acc[g][mt] = splat4(b1v[g]);
    f32x4 fca[4];
#pragma unroll
    for (int mt=0; mt<4; mt++) fca[mt] = splat4(fcbv);

    if (t > 0){
      GEMM(32, 16, h0cur, h1rd, Wb1i, Wb1h, acc, des, fca, 16);
      if (des && ucol < 63){
#pragma unroll
        for (int mt=0; mt<4; mt++)
#pragma unroll
          for (int r=0; r<4; r++){
            int row = wr*64 + mt*16 + quad*4 + r;
            out[((b0+row)*63 + ucol)*100 + (t-1)] = fca[mt][r];
          }
      }
    } else {
      GEMM(16, 16, h0cur, h0cur, Wb1i, Wb1i, acc, false, fcd, 0);
    }
#pragma unroll
    for (int mt=0; mt<4; mt++){
#pragma unroll
      for (int r=0; r<4; r++){
        float iv = sigm(acc[0][mt][r]);
        float fv = sigm(acc[1][mt][r]);
        float gv = tanhx(acc[2][mt][r]);
        float ov = sigm(acc[3][mt][r]);
        float cn = fv*c1[mt][r] + iv*gv;
        c1[mt][r] = cn;
        float hn = ov * tanhx(cn);
        int row = wr*64 + mt*16 + quad*4 + r;
        st_coh_u16(h1wr + (size_t)(b0+row)*HIDN + j*64 + ucol, f16bits(hn));
      }
    }
    // h1 stores drained by barrier(t+1) before any reader consumes them.
  }

  // ----- epilogue: y(99) from h1(99) (parity 1) -----
  barrier(SEQL);
  if (des){
    const f16* h1last = h1buf + (size_t)1*BATCH*HIDN + (size_t)b0*HIDN;
    f32x4 fca[4];
#pragma unroll
    for (int mt=0; mt<4; mt++) fca[mt] = splat4(fcbv);
    for (int kc=0; kc<16; kc++){
      __syncthreads();
      const unsigned int* q = (const unsigned int*)(h1last + kc*32 + Aoff);
      unsigned int r0 = ld_coh_u32(q+0);
      unsigned int r1 = ld_coh_u32(q+1);
      unsigned int r2 = ld_coh_u32(q+2);
      unsigned int r3 = ld_coh_u32(q+3);
      wait_vm0();
      unsigned int* d = (unsigned int*)&Ach[0][srA*40 + ssg];
      d[0]=r0; d[1]=r1; d[2]=r2; d[3]=r3;
      __syncthreads();
      half8 af[4];
#pragma unroll
      for (int mt=0; mt<4; mt++)
        af[mt] = *(const half8*)&Ach[0][(wr*64 + mt*16 + lc)*40 + quad*8];
      half8 fb = *(const half8*)(fcWp + boffB + kc*32);
#pragma unroll
      for (int mt=0; mt<4; mt++)
        fca[mt] = __builtin_amdgcn_mfma_f32_16x16x32_f16(af[mt], fb, fca[mt], 0, 0, 0);
    }
    if (ucol < 63){
#pragma unroll
      for (int mt=0; mt<4; mt++)
#pragma unroll
        for (int r=0; r<4; r++){
          int row = wr*64 + mt*16 + quad*4 + r;
          out[((b0+row)*63 + ucol)*100 + 99] = fca[mt][r];
        }
    }
  }
}

// ---------------------------------------------------------------------------
extern "C" void kernel_launch(void* const* d_in, const int* in_sizes, int n_in,
                              void* d_out, int out_size, void* d_ws, size_t ws_size,
                              hipStream_t stream)
{
  const int*   sl   = (const int*)  d_in[0];
  const int*   el   = (const int*)  d_in[1];
  const float* sc   = (const float*)d_in[2];
  const float* ec   = (const float*)d_in[3];
  const float* emb  = (const float*)d_in[4];
  const float* Wih0 = (const float*)d_in[5];
  const float* Whh0 = (const float*)d_in[6];
  const float* bih0 = (const float*)d_in[7];
  const float* bhh0 = (const float*)d_in[8];
  const float* Wih1 = (const float*)d_in[9];
  const float* Whh1 = (const float*)d_in[10];
  const float* bih1 = (const float*)d_in[11];
  const float* bhh1 = (const float*)d_in[12];
  const float* fcW  = (const float*)d_in[13];
  const float* fcb  = (const float*)d_in[14];

  char* ws = (char*)d_ws;
  float* xcatT = (float*)(ws + OFF_XCAT);
  f16*   x0ph  = (f16*)  (ws + OFF_X0PT);
  f16*   Wp0   = (f16*)  (ws + OFF_WP0);
  f16*   Wp1i  = (f16*)  (ws + OFF_WP1I);
  f16*   Wp1h  = (f16*)  (ws + OFF_WP1H);
  f16*   fcWp  = (f16*)  (ws + OFF_FCW);
  float* b1p   = (float*)(ws + OFF_B1P);
  f16*   h0b   = (f16*)  (ws + OFF_H0);
  f16*   h1b   = (f16*)  (ws + OFF_H1);
  unsigned int* flags = (unsigned int*)(ws + OFF_FLAGS);

  hipMemsetAsync(flags, 0, FLAG_BYTES, stream);
  k_xcat<<<dim3(16, 256), 256, 0, stream>>>(sl, el, sc, ec, emb, xcatT);
  k_pack<<<6216, 256, 0, stream>>>(Whh0, Wih1, Whh1, fcW, bih1, bhh1,
                                   Wp0, Wp1i, Wp1h, fcWp, b1p);
  k_x0<<<dim3(64, 16), 256, 0, stream>>>(xcatT, Wih0, bih0, bhh0, x0ph);
  k_lstm<<<256, 512, 0, stream>>>(x0ph, Wp0, Wp1i, Wp1h, fcWp, b1p, fcb,
                                  h0b, h1b, flags, (float*)d_out);
}